// Round 8
// baseline (337.051 us; speedup 1.0000x reference)
//
#include <hip/hip_runtime.h>

// Pin2PinAttraction: sum_i w[i] * ((x[a_i]-x[b_i])^2 + (y[a_i]-y[b_i])^2)
//
// r8: in-LDS access-order sort (no global scatter — r5/r6 showed scattered
// global writes cost 2-10x payload). Per 1024-pair chunk: counting-sort the
// 2048 endpoints by pin-slice (32 x 512KB) in LDS, gather slice-major dense,
// compute from LDS. Goal: co-resident blocks walk slices together -> each
// XCD L2 holds a few slices -> table fills 694 MB -> ~130-250 MB.

typedef int   i32x4 __attribute__((ext_vector_type(4)));
typedef int   i32x2 __attribute__((ext_vector_type(2)));
typedef float f32x2 __attribute__((ext_vector_type(2)));

#define NSLICE 32
#define CHUNK  1024            // pairs per chunk
#define NEND   (2 * CHUNK)     // endpoints per chunk
#define PPT    4               // pairs per thread = CHUNK / 256

// ---------------------------------------------------------------- pack
__global__ __launch_bounds__(256) void pack_xy_kernel(
    const float* __restrict__ pin_pos,
    f32x2*       __restrict__ xy,
    int num_pins)
{
    const int tid    = blockIdx.x * blockDim.x + threadIdx.x;
    const int stride = gridDim.x * blockDim.x;
    const float* __restrict__ xs = pin_pos;
    const float* __restrict__ ys = pin_pos + num_pins;
    for (int i = tid; i < num_pins; i += stride) {
        f32x2 v; v.x = xs[i]; v.y = ys[i];
        xy[i] = v;
    }
}

// ---------------------------------------------------------------- sorted gather
// Requires num_pins <= 2^21 (record = (pin<<11)|slot, slot < 2048).
__global__ __launch_bounds__(256) void p2p_sorted_kernel(
    const f32x2* __restrict__ xy,      // [num_pins] packed {x,y}
    const float* __restrict__ weights, // [num_pairs]
    const int*   __restrict__ pairs,   // [2*num_pairs] interleaved
    float*       __restrict__ out,     // [1]
    int num_pairs, int shift)
{
    const int tid = threadIdx.x;
    const i32x2* __restrict__ pr = (const i32x2*)pairs;

    __shared__ unsigned s_rec[NEND];   // 8 KB  (pin<<11)|slot, slice-sorted
    __shared__ f32x2    s_xy[NEND];    // 16 KB gathered coords, by slot
    __shared__ int      hist[NSLICE];
    __shared__ int      cursor[NSLICE];
    __shared__ float    wave_sums[4];

    const int nchunks = (num_pairs + CHUNK - 1) / CHUNK;
    float acc = 0.0f;

    for (int c = blockIdx.x; c < nchunks; c += gridDim.x) {
        const int p0 = c * CHUNK;
        const int n  = min(CHUNK, num_pairs - p0);

        if (tid < NSLICE) hist[tid] = 0;
        __syncthreads();

        // phase 1: load pairs (coalesced, nt) into regs + slice histogram
        int pa[PPT], pb[PPT];
#pragma unroll
        for (int k = 0; k < PPT; ++k) {
            const int l = tid + 256 * k;
            if (l < n) {
                i32x2 p = __builtin_nontemporal_load(pr + p0 + l);
                pa[k] = p.x; pb[k] = p.y;
                atomicAdd(&hist[p.x >> shift], 1);
                atomicAdd(&hist[p.y >> shift], 1);
            } else { pa[k] = 0; pb[k] = 0; }
        }
        __syncthreads();

        // phase 2: exclusive scan of 32 bins (lanes 0..31 of wave 0)
        if (tid < NSLICE) {
            int v = hist[tid];
            int pfx = v;
            for (int d = 1; d < NSLICE; d <<= 1) {
                int u = __shfl_up(pfx, d, 64);
                if (tid >= d) pfx += u;
            }
            cursor[tid] = pfx - v;     // exclusive prefix
        }
        __syncthreads();

        // phase 3: scatter records into slice-sorted LDS order
#pragma unroll
        for (int k = 0; k < PPT; ++k) {
            const int l = tid + 256 * k;
            if (l < n) {
                const int a = pa[k], b = pb[k];
                int posa = atomicAdd(&cursor[a >> shift], 1);
                s_rec[posa] = ((unsigned)a << 11) | (unsigned)(2 * l);
                int posb = atomicAdd(&cursor[b >> shift], 1);
                s_rec[posb] = ((unsigned)b << 11) | (unsigned)(2 * l + 1);
            }
        }
        __syncthreads();

        // phase 4: dense slice-major gather -> s_xy[slot]
        if (n == CHUNK) {
            unsigned r[8];
#pragma unroll
            for (int k = 0; k < 8; ++k) r[k] = s_rec[tid + 256 * k];
            f32x2 v[8];
#pragma unroll
            for (int k = 0; k < 8; ++k) v[k] = xy[r[k] >> 11];  // 8 indep gathers
#pragma unroll
            for (int k = 0; k < 8; ++k) s_xy[r[k] & 2047u] = v[k];
        } else {
            const int ne = 2 * n;
            for (int e = tid; e < ne; e += 256) {
                unsigned r = s_rec[e];
                s_xy[r & 2047u] = xy[r >> 11];
            }
        }
        __syncthreads();

        // phase 5: compute from LDS + stream weights (coalesced, nt)
#pragma unroll
        for (int k = 0; k < PPT; ++k) {
            const int l = tid + 256 * k;
            if (l < n) {
                f32x2 A = s_xy[2 * l], B = s_xy[2 * l + 1];
                float w = __builtin_nontemporal_load(weights + p0 + l);
                float dx = A.x - B.x, dy = A.y - B.y;
                acc += w * (dx * dx + dy * dy);
            }
        }
        __syncthreads();               // LDS reused next chunk
    }

    // block reduce + single atomic
    for (int off = 32; off > 0; off >>= 1)
        acc += __shfl_down(acc, off, 64);
    const int lane = tid & 63, wid = tid >> 6;
    if (lane == 0) wave_sums[wid] = acc;
    __syncthreads();
    if (tid == 0) {
        float s = wave_sums[0] + wave_sums[1] + wave_sums[2] + wave_sums[3];
        atomicAdd(out, s);
    }
}

// ---------------------------------------------------------------- r3 gather (fallback)
__global__ __launch_bounds__(256) void p2p_gather_kernel(
    const f32x2* __restrict__ xy,
    const float* __restrict__ weights,
    const int*   __restrict__ pairs,
    float*       __restrict__ out,
    int num_pairs)
{
    const int tid    = blockIdx.x * blockDim.x + threadIdx.x;
    const int stride = gridDim.x * blockDim.x;
    float acc = 0.0f;
    const i32x4* __restrict__ pairs4 = (const i32x4*)pairs;
    const f32x2* __restrict__ w2     = (const f32x2*)weights;
    const int n2 = num_pairs >> 1;
    for (int i = tid; i < n2; i += stride) {
        i32x4 p = __builtin_nontemporal_load(pairs4 + i);
        f32x2 w = __builtin_nontemporal_load(w2 + i);
        f32x2 A0 = xy[p.x], B0 = xy[p.y];
        f32x2 A1 = xy[p.z], B1 = xy[p.w];
        float dx0 = A0.x - B0.x, dy0 = A0.y - B0.y;
        float dx1 = A1.x - B1.x, dy1 = A1.y - B1.y;
        acc += w.x * (dx0 * dx0 + dy0 * dy0);
        acc += w.y * (dx1 * dx1 + dy1 * dy1);
    }
    if ((num_pairs & 1) && tid == 0) {
        int a = pairs[2 * (num_pairs - 1)];
        int b = pairs[2 * (num_pairs - 1) + 1];
        f32x2 A = xy[a], B = xy[b];
        float dx = A.x - B.x, dy = A.y - B.y;
        acc += weights[num_pairs - 1] * (dx * dx + dy * dy);
    }
    for (int off = 32; off > 0; off >>= 1)
        acc += __shfl_down(acc, off, 64);
    __shared__ float wave_sums[4];
    const int lane = threadIdx.x & 63, wid = threadIdx.x >> 6;
    if (lane == 0) wave_sums[wid] = acc;
    __syncthreads();
    if (threadIdx.x == 0) {
        float s = wave_sums[0] + wave_sums[1] + wave_sums[2] + wave_sums[3];
        atomicAdd(out, s);
    }
}

// ---------------------------------------------------------------- direct (no-ws)
__global__ __launch_bounds__(256) void p2p_direct_kernel(
    const float* __restrict__ pin_pos,
    const float* __restrict__ weights,
    const int*   __restrict__ pairs,
    float*       __restrict__ out,
    int num_pins, int num_pairs)
{
    const float* __restrict__ xs = pin_pos;
    const float* __restrict__ ys = pin_pos + num_pins;
    const int tid    = blockIdx.x * blockDim.x + threadIdx.x;
    const int stride = gridDim.x * blockDim.x;
    float acc = 0.0f;
    for (int i = tid; i < num_pairs; i += stride) {
        int a = pairs[2 * i], b = pairs[2 * i + 1];
        float dx = xs[a] - xs[b], dy = ys[a] - ys[b];
        acc += weights[i] * (dx * dx + dy * dy);
    }
    for (int off = 32; off > 0; off >>= 1)
        acc += __shfl_down(acc, off, 64);
    __shared__ float wave_sums[4];
    const int lane = threadIdx.x & 63, wid = threadIdx.x >> 6;
    if (lane == 0) wave_sums[wid] = acc;
    __syncthreads();
    if (threadIdx.x == 0) {
        float s = wave_sums[0] + wave_sums[1] + wave_sums[2] + wave_sums[3];
        atomicAdd(out, s);
    }
}

// ---------------------------------------------------------------- launch
extern "C" void kernel_launch(void* const* d_in, const int* in_sizes, int n_in,
                              void* d_out, int out_size, void* d_ws, size_t ws_size,
                              hipStream_t stream) {
    const float* pin_pos = (const float*)d_in[0];
    const float* weights = (const float*)d_in[1];
    const int*   pairs   = (const int*)d_in[2];
    // d_in[3] = pin_mask (unused by reference)

    const int num_pins  = in_sizes[0] / 2;
    const int num_pairs = in_sizes[1];

    float* out = (float*)d_out;
    hipMemsetAsync(out, 0, sizeof(float), stream);  // d_out poisoned each call

    const int block = 256;

    // 32 slices: smallest shift with (num_pins-1)>>shift <= 31
    int shift = 0;
    while (((unsigned)(num_pins - 1) >> shift) > 31u) ++shift;

    const size_t xy_bytes = (size_t)num_pins * sizeof(f32x2);

    if (ws_size >= xy_bytes && num_pins <= (1 << 21)) {
        f32x2* xy = (f32x2*)d_ws;
        pack_xy_kernel<<<2048, block, 0, stream>>>(pin_pos, xy, num_pins);
        const int nchunks = (num_pairs + CHUNK - 1) / CHUNK;
        const int grid = nchunks < 1536 ? nchunks : 1536;  // all co-resident (6 blk/CU LDS cap)
        p2p_sorted_kernel<<<grid, block, 0, stream>>>(
            xy, weights, pairs, out, num_pairs, shift);
    } else if (ws_size >= xy_bytes) {
        f32x2* xy = (f32x2*)d_ws;
        pack_xy_kernel<<<2048, block, 0, stream>>>(pin_pos, xy, num_pins);
        p2p_gather_kernel<<<2048, block, 0, stream>>>(
            xy, weights, pairs, out, num_pairs);
    } else {
        p2p_direct_kernel<<<2048, block, 0, stream>>>(
            pin_pos, weights, pairs, out, num_pins, num_pairs);
    }
}